// Round 5
// baseline (483.004 us; speedup 1.0000x reference)
//
#include <hip/hip_runtime.h>
#include <hip/hip_bf16.h>

#define CC 96

typedef short short8  __attribute__((ext_vector_type(8)));
typedef short short4v __attribute__((ext_vector_type(4)));
typedef float f32x4   __attribute__((ext_vector_type(4)));

static __device__ __forceinline__ ushort f2bf(float f) {
  __hip_bfloat16 h = __float2bfloat16(f);
  return *reinterpret_cast<ushort*>(&h);
}
static __device__ __forceinline__ float bf2f(ushort u) {
  union { unsigned int u; float f; } v; v.u = ((unsigned int)u) << 16; return v.f;
}

// ---------------- prep: pack all weights ----------------
// qkvp  [h][ks][nt][lane][8] bf16 (36864): B-frags QKV GEMM (per-head N=96: q32|k32|v32, d>=24 zero)
// projp [h][nt][lane][8]    bf16 (12288): B-frags proj, per-head K=32 (d>=24 zero)
// w2p   conv3 B-frags        bf16 (82944)
// w1p   [ks][12nt][lane][8]  bf16 (18432): conv1x1 B-frags (N=192)
__global__ void prep_kernel(const float* __restrict__ qkv_w,
                            const float* __restrict__ proj_w,
                            const float* __restrict__ w2w,
                            const float* __restrict__ w1w,
                            __hip_bfloat16* __restrict__ qkvp,
                            __hip_bfloat16* __restrict__ projp,
                            __hip_bfloat16* __restrict__ w2p,
                            __hip_bfloat16* __restrict__ w1p)
{
  const int i = blockIdx.x*256 + threadIdx.x;
  if (i < 36864) {
    const int e = i & 7, lane = (i >> 3) & 63;
    const int rest = i >> 9;           // (h*3+ks)*6+nt
    const int nt = rest % 6, r2 = rest / 6;
    const int ks = r2 % 3, h = r2 / 3;
    const int col = nt*16 + (lane & 15);
    const int sec = col >> 5, d = col & 31;
    const int c = ks*32 + (lane >> 4)*8 + e;
    const float val = (d < 24) ? qkv_w[(sec*96 + h*24 + d)*96 + c] : 0.f;
    qkvp[i] = __float2bfloat16(val);
  }
  const int j = i - 36864;
  if (j >= 0 && j < 12288) {
    const int e = j & 7, lane = (j >> 3) & 63;
    const int rest = j >> 9;           // h*6+nt
    const int nt = rest % 6, h = rest / 6;
    const int oc = nt*16 + (lane & 15);
    const int dl = (lane >> 4)*8 + e;  // 0..31
    const float val = (dl < 24) ? proj_w[oc*96 + h*24 + dl] : 0.f;
    projp[j] = __float2bfloat16(val);
  }
  const int k = i - 49152;
  if (k >= 0 && k < 82944) {
    const int e = k & 7;
    const int lane = (k >> 3) & 63;
    const int rest = k >> 9;           // (tap*3+kc)*6+nf
    const int nf = rest % 6;
    const int r2 = rest / 6;
    const int kc = r2 % 3;
    const int tap = r2 / 3;
    const int cidx = kc*32 + (lane >> 4)*8 + e;
    const int oc = nf*16 + (lane & 15);
    const int ky = tap / 3, kx = tap - ky*3;
    w2p[k] = __float2bfloat16(w2w[((oc*96 + cidx)*3 + ky)*3 + kx]);
  }
  const int m = i - 132096;
  if (m >= 0 && m < 18432) {
    const int e = m & 7, lane = (m >> 3) & 63;
    const int rest = m >> 9;           // ks*12+nt
    const int nt = rest % 12, ks = rest / 12;
    const int oc = nt*16 + (lane & 15);
    const int c  = ks*32 + (lane >> 4)*8 + e;
    w1p[m] = __float2bfloat16(w1w[oc*96 + c]);
  }
}

// ---------------- Kernel 1: windowed MHA via MFMA, cooperative heads ----------------
// 4 waves share one head-region; heads sequential. LDS 31.1KB -> 5 blocks/CU.
__global__ __launch_bounds__(256, 5) void attn_kernel(
    const float* __restrict__ x,
    const float* __restrict__ norm_w,
    const __hip_bfloat16* __restrict__ qkvp,
    const float* __restrict__ qkv_b,
    const __hip_bfloat16* __restrict__ projp,
    const float* __restrict__ proj_b,
    const float* __restrict__ bias_table,
    float* __restrict__ out)
{
  extern __shared__ char smem[];
  ushort* xn   = (ushort*)smem;              // [64][104] bf16 xn; later outT[96][68]
  ushort* Qs   = (ushort*)(smem + 13312);    // [64][32]
  ushort* Ks   = (ushort*)(smem + 17408);    // [64][32]
  ushort* Vt   = (ushort*)(smem + 21504);    // [32 d][72 tok] stride 144B
  ushort* oh   = (ushort*)(smem + 26112);    // [64][32] per-head o
  float*  btab = (float*)(smem + 30208);     // [225]
  ushort* Ps   = Qs;                         // [64] rows x 128B, overlays Q+K

  const int wid = (blockIdx.x & 7)*512 + (blockIdx.x >> 3);   // XCD-chunked swizzle
  const int b  = wid >> 10;
  const int wy = (wid >> 5) & 31;
  const int wx = wid & 31;
  const int t  = threadIdx.x;
  const int y0 = wy*8, x0 = wx*8;
  const int l  = t & 63;
  const int w  = __builtin_amdgcn_readfirstlane(t >> 6);
  const int lr = l & 15, g = l >> 4;

  for (int i = t; i < 225; i += 256) btab[i] = bias_table[i];

  // ---- P1: window -> xn bf16 (raw) ----
  for (int e = t; e < 1536; e += 256) {
    const int c = e >> 4, q4 = e & 15;
    const int ty = q4 >> 1, tx0 = (q4 & 1) << 2;
    const float4 v = *(const float4*)(x + (size_t)(b*CC+c)*65536 + (size_t)(y0+ty)*256 + x0 + tx0);
    const int n = ty*8 + tx0;
    xn[(n+0)*104+c] = f2bf(v.x); xn[(n+1)*104+c] = f2bf(v.y);
    xn[(n+2)*104+c] = f2bf(v.z); xn[(n+3)*104+c] = f2bf(v.w);
  }
  __syncthreads();

  // ---- P1.5: RMSNorm in place (sumsq from bf16) ----
  {
    const int n = t >> 2, c0 = (t & 3) * 24;
    short8 raw[3];
    #pragma unroll
    for (int k2 = 0; k2 < 3; k2++) raw[k2] = *(const short8*)(xn + n*104 + c0 + k2*8);
    float xv[24]; float ss = 0.f;
    #pragma unroll
    for (int k2 = 0; k2 < 3; k2++)
      #pragma unroll
      for (int q = 0; q < 8; q++) { const float u = bf2f((ushort)raw[k2][q]); xv[k2*8+q] = u; ss += u*u; }
    ss += __shfl_xor(ss, 1);
    ss += __shfl_xor(ss, 2);
    const float s = rsqrtf(ss * (1.f/96.f) + 1e-6f);
    #pragma unroll
    for (int k2 = 0; k2 < 3; k2++) {
      short8 pk;
      #pragma unroll
      for (int q = 0; q < 8; q++) pk[q] = (short)f2bf(xv[k2*8+q] * s * norm_w[c0 + k2*8 + q]);
      *(short8*)(xn + n*104 + c0 + k2*8) = pk;
    }
  }

  f32x4 pacc[6];
  #pragma unroll
  for (int nt = 0; nt < 6; nt++) pacc[nt] = (f32x4)0.f;

  for (int h = 0; h < 4; h++) {
    __syncthreads();   // (a) protect Q/K(Ps)/Vt/oh reuse; h=0: after-norm barrier

    // ---- QKV: wave w does mtile w (tokens 16w..16w+15), N=96, K=96 ----
    f32x4 acc[6];
    #pragma unroll
    for (int nt = 0; nt < 6; nt++) acc[nt] = (f32x4)0.f;
    #pragma unroll
    for (int ks = 0; ks < 3; ks++) {
      const short8 afr = *(const short8*)((const char*)xn + (lr + w*16)*208 + g*16 + ks*64);
      #pragma unroll
      for (int nt = 0; nt < 6; nt++) {
        const short8 bfr = *(const short8*)(qkvp + ((h*3+ks)*6+nt)*512 + l*8);
        acc[nt] = __builtin_amdgcn_mfma_f32_16x16x32_bf16(afr, bfr, acc[nt], 0, 0, 0);
      }
    }
    // write Q,K (u16) and Vt (short4v transposed)
    #pragma unroll
    for (int nt = 0; nt < 4; nt++) {
      const int sec  = nt >> 1;
      const int dcol = lr + (nt & 1)*16;
      ushort* dst = sec ? Ks : Qs;
      const float bias = (dcol < 24) ? qkv_b[sec*96 + h*24 + dcol] : 0.f;
      #pragma unroll
      for (int r = 0; r < 4; r++) {
        const int row = g*4 + r + w*16;
        const float val = (dcol < 24) ? (acc[nt][r] + bias) : 0.f;
        dst[row*32 + dcol] = f2bf(val);
      }
    }
    #pragma unroll
    for (int nt = 4; nt < 6; nt++) {
      const int vd = lr + (nt-4)*16;
      const float bias = (vd < 24) ? qkv_b[192 + h*24 + vd] : 0.f;
      short4v pk;
      #pragma unroll
      for (int r = 0; r < 4; r++) {
        const float val = (vd < 24) ? (acc[nt][r] + bias) : 0.f;
        pk[r] = (short)f2bf(val);
      }
      *(short4v*)((char*)Vt + vd*144 + (g*4 + w*16)*2) = pk;
    }
    __syncthreads();   // (b) Q/K/Vt complete

    // ---- scores: rows 16w, all K ----
    f32x4 sacc[4];
    {
      const short8 qf = *(const short8*)((char*)Qs + (lr + w*16)*64 + g*16);
      #pragma unroll
      for (int nt = 0; nt < 4; nt++) {
        const short8 kf = *(const short8*)((char*)Ks + (lr + nt*16)*64 + g*16);
        sacc[nt] = __builtin_amdgcn_mfma_f32_16x16x32_bf16(qf, kf, (f32x4)0.f, 0, 0, 0);
      }
    }
    __syncthreads();   // (c) scores reads done; P may overwrite Q/K

    // ---- softmax rows 16w -> P swizzled ----
    {
      const float SCALE = 0.20412414523193154f;
      int bk[4];
      #pragma unroll
      for (int nt = 0; nt < 4; nt++) {
        const int k = lr + nt*16;
        bk[nt] = 112 - ((k >> 3)*15 + (k & 7));
      }
      #pragma unroll
      for (int r = 0; r < 4; r++) {
        const int q  = g*4 + r + w*16;
        const int aq = (q >> 3)*15 + (q & 7);
        float v[4];
        #pragma unroll
        for (int nt = 0; nt < 4; nt++) v[nt] = sacc[nt][r]*SCALE + btab[aq + bk[nt]];
        float mx = fmaxf(fmaxf(v[0], v[1]), fmaxf(v[2], v[3]));
        mx = fmaxf(mx, __shfl_xor(mx, 1));
        mx = fmaxf(mx, __shfl_xor(mx, 2));
        mx = fmaxf(mx, __shfl_xor(mx, 4));
        mx = fmaxf(mx, __shfl_xor(mx, 8));
        float e[4], s = 0.f;
        #pragma unroll
        for (int nt = 0; nt < 4; nt++) { e[nt] = __expf(v[nt]-mx); s += e[nt]; }
        s += __shfl_xor(s, 1); s += __shfl_xor(s, 2);
        s += __shfl_xor(s, 4); s += __shfl_xor(s, 8);
        const float rinv = 1.0f / s;
        const int sw = (q & 7) << 4;
        #pragma unroll
        for (int nt = 0; nt < 4; nt++) {
          const int kk = (lr + nt*16)*2;
          *(ushort*)((char*)Ps + q*128 + (kk ^ sw)) = f2bf(e[nt]*rinv);
        }
      }
    }

    // ---- PV: own P rows x all Vt -> oh rows 16w ----
    {
      f32x4 oacc[2];
      oacc[0] = (f32x4)0.f; oacc[1] = (f32x4)0.f;
      const int row = lr + w*16;
      #pragma unroll
      for (int ks = 0; ks < 2; ks++) {
        const short8 pf = *(const short8*)((char*)Ps + row*128 + ((g*16 + ks*64) ^ ((row & 7) << 4)));
        #pragma unroll
        for (int nt = 0; nt < 2; nt++) {
          const short8 vf = *(const short8*)((char*)Vt + (lr+nt*16)*144 + g*16 + ks*64);
          oacc[nt] = __builtin_amdgcn_mfma_f32_16x16x32_bf16(pf, vf, oacc[nt], 0, 0, 0);
        }
      }
      #pragma unroll
      for (int nt = 0; nt < 2; nt++) {
        const int d0 = lr + nt*16;
        #pragma unroll
        for (int r = 0; r < 4; r++) {
          const int rw = g*4 + r + w*16;
          oh[rw*32 + d0] = f2bf((d0 < 24) ? oacc[nt][r] : 0.f);
        }
      }
    }

    // ---- proj partial: own oh rows, per-head K=32 ----
    {
      const short8 af = *(const short8*)((char*)oh + (lr + w*16)*64 + g*16);
      #pragma unroll
      for (int nt = 0; nt < 6; nt++) {
        const short8 bf = *(const short8*)(projp + (h*6+nt)*512 + l*8);
        pacc[nt] = __builtin_amdgcn_mfma_f32_16x16x32_bf16(af, bf, pacc[nt], 0, 0, 0);
      }
    }
  }

  __syncthreads();   // (f) all xn reads done -> xn becomes outT[96][68]
  {
    ushort* oT = xn;
    #pragma unroll
    for (int nt = 0; nt < 6; nt++) {
      const int oc = lr + nt*16;
      const float bias = proj_b[oc];
      short4v pk;
      #pragma unroll
      for (int r = 0; r < 4; r++) pk[r] = (short)f2bf(pacc[nt][r] + bias);
      *(short4v*)((char*)oT + oc*136 + (g*4 + w*16)*2) = pk;
    }
  }
  __syncthreads();   // (g)

  // ---- epilogue: out = x + attn ----
  {
    const ushort* oT = xn;
    #pragma unroll
    for (int k2 = 0; k2 < 6; k2++) {
      const int v = t + k2*256;
      const int oc = v >> 4, pq = v & 15;
      const int ty = pq >> 1, tx4 = (pq & 1) << 2;
      const int pl = ty*8 + tx4;
      const short4v ov = *(const short4v*)((const char*)oT + oc*136 + pl*2);
      const size_t gidx = (size_t)(b*CC+oc)*65536 + (size_t)(y0+ty)*256 + x0 + tx4;
      float4 xv = *(const float4*)(x + gidx);
      float4 res;
      res.x = xv.x + bf2f((ushort)ov[0]);
      res.y = xv.y + bf2f((ushort)ov[1]);
      res.z = xv.z + bf2f((ushort)ov[2]);
      res.w = xv.w + bf2f((ushort)ov[3]);
      *(float4*)(out + gidx) = res;
    }
  }
}

// ---------------- Kernel 2: RMSNorm + conv1x1 + GLU via MFMA -> y bf16 [b][hw][96] ----------------
__global__ __launch_bounds__(256, 2) void mlp1_kernel(
    const float* __restrict__ x1,
    const float* __restrict__ mlp_norm_w,
    const __hip_bfloat16* __restrict__ w1p,   // [ks][12][64][8]
    const float* __restrict__ w1_b,
    __hip_bfloat16* __restrict__ y)           // [b][hw][96]
{
  __shared__ ushort xn[128*104];
  const int blk = blockIdx.x;
  const int b   = blk >> 9;
  const int p0  = (blk & 511) << 7;
  const int t   = threadIdx.x;
  const int l   = t & 63;
  const int w   = __builtin_amdgcn_readfirstlane(t >> 6);
  const int lr  = l & 15, g = l >> 4;

  {
    const int p = t >> 1, half = t & 1;
    const float* xp = x1 + (size_t)(b*CC + half*48)*65536 + p0 + p;
    float xv[48];
    float ss = 0.f;
    #pragma unroll
    for (int i = 0; i < 48; i++) { xv[i] = xp[(size_t)i*65536]; ss += xv[i]*xv[i]; }
    ss += __shfl_xor(ss, 1);
    const float s = rsqrtf(ss*(1.f/96.f) + 1e-6f);
    #pragma unroll
    for (int i = 0; i < 48; i += 2) {
      const int c = half*48 + i;
      union { ushort u[2]; uint v; } pk;
      pk.u[0] = f2bf(xv[i]   * s * mlp_norm_w[c]);
      pk.u[1] = f2bf(xv[i+1] * s * mlp_norm_w[c+1]);
      *(uint*)(&xn[p*104 + c]) = pk.v;
    }
  }
  // wave-private rows -> no barrier needed before GEMM

  f32x4 acc[2][12];
  #pragma unroll
  for (int m2 = 0; m2 < 2; m2++)
    #pragma unroll
    for (int nt = 0; nt < 12; nt++) acc[m2][nt] = (f32x4)0.f;

  #pragma unroll
  for (int ks = 0; ks < 3; ks++) {
    short8 afr[2];
    #pragma unroll
    for (int m2 = 0; m2 < 2; m2++)
      afr[m2] = *(const short8*)((const char*)xn + (lr + (w*2+m2)*16)*208 + g*16 + ks*64);
    #pragma unroll
    for (int nt = 0; nt < 12; nt++) {
      const short8 bfr = *(const short8*)(w1p + ((ks*12+nt)*64 + l)*8);
      #pragma unroll
      for (int m2 = 0; m2 < 2; m2++)
        acc[m2][nt] = __builtin_amdgcn_mfma_f32_16x16x32_bf16(afr[m2], bfr, acc[m2][nt], 0, 0, 0);
    }
  }

  #pragma unroll
  for (int m2 = 0; m2 < 2; m2++)
    #pragma unroll
    for (int nt = 0; nt < 6; nt++) {
      const int oc = nt*16 + lr;
      const float ab = w1_b[oc], gb = w1_b[96+oc];
      #pragma unroll
      for (int r = 0; r < 4; r++) {
        const int row = (w*2+m2)*16 + g*4 + r;
        const float a  = acc[m2][nt][r]   + ab;
        const float gg = acc[m2][nt+6][r] + gb;
        xn[row*104 + oc] = f2bf(a / (1.f + __expf(-gg)));
      }
    }
  __syncthreads();

  __hip_bfloat16* yp = y + ((size_t)(b*65536 + p0))*96;
  #pragma unroll
  for (int k2 = 0; k2 < 6; k2++) {
    const int e = t + k2*256;
    const int p = e / 12, ch = e - p*12;
    const short8 v = *(const short8*)(&xn[p*104 + ch*8]);
    *(short8*)((ushort*)yp + p*96 + ch*8) = v;
  }
}

// ---------------- Kernel 3: conv3x3 via MFMA implicit GEMM + leaky + residual ----------------
__global__ __launch_bounds__(256) void conv3_kernel(
    const __hip_bfloat16* __restrict__ y,    // [b][hw][96]
    const __hip_bfloat16* __restrict__ w2p,
    const float* __restrict__ w2_b,
    float* __restrict__ xout)
{
  extern __shared__ char smem[];
  ushort* A = (ushort*)smem;
  float*  O = (float*)smem;

  const int bid = (blockIdx.x & 7)*256 + (blockIdx.x >> 3);   // XCD-chunked swizzle
  const int b   = bid >> 9;
  const int rp  = (bid >> 2) & 127;
  const int ch  = bid & 3;
  const int px0 = ch << 6;
  const int t   = threadIdx.x;
  const int w   = __builtin_amdgcn_readfirstlane(t >> 6);
  const int l   = t & 63;
  const int m15 = l & 15, lh = l >> 4;

  for (int e = t; e < 3168; e += 256) {
    const int seg  = e / 12;
    const int part = e - seg*12;
    const int ky = seg / 66;
    const int px = seg - ky*66;
    const int gy = min(255, max(0, 2*rp + ky - 1));
    const int gx = min(255, max(0, px0 + px - 1));
    const short8 v = *(const short8*)(y + ((size_t)(b*65536 + gy*256 + gx))*96 + part*8);
    *(short8*)(A + seg*104 + part*8) = v;
  }
  __syncthreads();

  f32x4 acc0[6], acc1[6];
  #pragma unroll
  for (int nf = 0; nf < 6; ++nf) { acc0[nf] = (f32x4)0.f; acc1[nf] = (f32x4)0.f; }

  for (int tap = 0; tap < 9; ++tap) {
    const int ky = tap / 3, kx = tap - ky*3;
    for (int kc = 0; kc < 3; ++kc) {
      const int cb = kc*32 + lh*8;
      const short8 a0 = *(const short8*)(A + ((ky  )*66 + 16*w + m15 + kx)*104 + cb);
      const short8 a1 = *(const short8*)(A + ((ky+1)*66 + 16*w + m15 + kx)*104 + cb);
      const short8* bp = (const short8*)w2p + ((size_t)(tap*3 + kc)*6)*64 + l;
      #pragma unroll
      for (int nf = 0; nf < 6; ++nf) {
        const short8 bf = bp[nf*64];
        acc0[nf] = __builtin_amdgcn_mfma_f32_16x16x32_bf16(a0, bf, acc0[nf], 0, 0, 0);
        acc1[nf] = __builtin_amdgcn_mfma_f32_16x16x32_bf16(a1, bf, acc1[nf], 0, 0, 0);
      }
    }
  }
  __syncthreads();

  {
    const int jb = 16*w + lh*4;
    #pragma unroll
    for (int nf = 0; nf < 6; ++nf) {
      const int oc = nf*16 + m15;
      *(f32x4*)(O + oc*132 + jb)      = acc0[nf];
      *(f32x4*)(O + oc*132 + 64 + jb) = acc1[nf];
    }
  }
  __syncthreads();

  for (int e = t; e < 3072; e += 256) {
    const int oc = e >> 5;
    const int j  = (e & 31) * 4;
    f32x4 v = *(const f32x4*)(O + oc*132 + j);
    const float bb = w2_b[oc];
    const int gy = 2*rp + (j >> 6);
    const int px = px0 + (j & 63);
    float* op = xout + ((size_t)(b*CC + oc))*65536 + (size_t)gy*256 + px;
    f32x4 r = *(const f32x4*)op;
    #pragma unroll
    for (int q = 0; q < 4; ++q) {
      float u = v[q] + bb;
      u = (u >= 0.f) ? u : 0.1f*u;
      r[q] += u;
    }
    *(f32x4*)op = r;
  }
}

extern "C" void kernel_launch(void* const* d_in, const int* in_sizes, int n_in,
                              void* d_out, int out_size, void* d_ws, size_t ws_size,
                              hipStream_t stream)
{
  (void)in_sizes; (void)n_in; (void)out_size; (void)ws_size;
  const float* x      = (const float*)d_in[0];
  const float* norm_w = (const float*)d_in[1];
  const float* qkv_w  = (const float*)d_in[2];
  const float* qkv_b  = (const float*)d_in[3];
  const float* proj_w = (const float*)d_in[4];
  const float* proj_b = (const float*)d_in[5];
  const float* btab   = (const float*)d_in[6];
  const float* mlpnw  = (const float*)d_in[7];
  const float* w1w    = (const float*)d_in[8];
  const float* w1b    = (const float*)d_in[9];
  const float* w2w    = (const float*)d_in[10];
  const float* w2b    = (const float*)d_in[11];
  float* out = (float*)d_out;

  char* ws = (char*)d_ws;
  __hip_bfloat16* y     = (__hip_bfloat16*)ws;                    // 50,331,648 B
  __hip_bfloat16* w2p   = (__hip_bfloat16*)(ws + 50331648);       // 165,888 B
  __hip_bfloat16* qkvp  = (__hip_bfloat16*)(ws + 50497536);       // 73,728 B
  __hip_bfloat16* projp = (__hip_bfloat16*)(ws + 50571264);       // 24,576 B
  __hip_bfloat16* w1p   = (__hip_bfloat16*)(ws + 50595840);       // 36,864 B

  prep_kernel<<<588, 256, 0, stream>>>(qkv_w, proj_w, w2w, w1w, qkvp, projp, w2p, w1p);

  attn_kernel<<<4096, 256, 31108, stream>>>(x, norm_w, qkvp, qkv_b, projp, proj_b, btab, out);
  mlp1_kernel<<<2048, 256, 0, stream>>>(out, mlpnw, w1p, w1b, y);
  conv3_kernel<<<2048, 256, 54912, stream>>>(y, w2p, w2b, out);
}

// Round 7
// 333.737 us; speedup vs baseline: 1.4473x; 1.4473x over previous
//
#include <hip/hip_runtime.h>
#include <hip/hip_bf16.h>

#define CC 96

typedef short short8  __attribute__((ext_vector_type(8)));
typedef short short4v __attribute__((ext_vector_type(4)));
typedef float f32x4   __attribute__((ext_vector_type(4)));

static __device__ __forceinline__ ushort f2bf(float f) {
  __hip_bfloat16 h = __float2bfloat16(f);
  return *reinterpret_cast<ushort*>(&h);
}
static __device__ __forceinline__ float bf2f(ushort u) {
  union { unsigned int u; float f; } v; v.u = ((unsigned int)u) << 16; return v.f;
}

// ---------------- prep: pack all weights (R4 layout) ----------------
// qkvp  [h][ks][nt][lane][8] bf16 (36864): B-frags QKV GEMM (per-head N=96: q32|k32|v32, d>=24 zero)
// projp [ks][nt][lane][8]    bf16 (9216):  B-frags proj, K=96
// w2p   conv3 B-frags        bf16 (82944)
// w1p   [ks][12nt][lane][8]  bf16 (18432): conv1x1 B-frags (N=192)
__global__ void prep_kernel(const float* __restrict__ qkv_w,
                            const float* __restrict__ proj_w,
                            const float* __restrict__ w2w,
                            const float* __restrict__ w1w,
                            __hip_bfloat16* __restrict__ qkvp,
                            __hip_bfloat16* __restrict__ projp,
                            __hip_bfloat16* __restrict__ w2p,
                            __hip_bfloat16* __restrict__ w1p)
{
  const int i = blockIdx.x*256 + threadIdx.x;
  if (i < 36864) {
    const int e = i & 7, lane = (i >> 3) & 63;
    const int rest = i >> 9;           // (h*3+ks)*6+nt
    const int nt = rest % 6, r2 = rest / 6;
    const int ks = r2 % 3, h = r2 / 3;
    const int col = nt*16 + (lane & 15);
    const int sec = col >> 5, d = col & 31;
    const int c = ks*32 + (lane >> 4)*8 + e;
    const float val = (d < 24) ? qkv_w[(sec*96 + h*24 + d)*96 + c] : 0.f;
    qkvp[i] = __float2bfloat16(val);
  }
  const int j = i - 36864;
  if (j >= 0 && j < 9216) {
    const int e = j & 7, lane = (j >> 3) & 63;
    const int rest = j >> 9;           // ks*6+nt
    const int nt = rest % 6, ks = rest / 6;
    const int oc = nt*16 + (lane & 15);
    const int dd = ks*32 + (lane >> 4)*8 + e;
    projp[j] = __float2bfloat16(proj_w[oc*96 + dd]);
  }
  const int k = i - 46080;
  if (k >= 0 && k < 82944) {
    const int e = k & 7;
    const int lane = (k >> 3) & 63;
    const int rest = k >> 9;           // (tap*3+kc)*6+nf
    const int nf = rest % 6;
    const int r2 = rest / 6;
    const int kc = r2 % 3;
    const int tap = r2 / 3;
    const int cidx = kc*32 + (lane >> 4)*8 + e;
    const int oc = nf*16 + (lane & 15);
    const int ky = tap / 3, kx = tap - ky*3;
    w2p[k] = __float2bfloat16(w2w[((oc*96 + cidx)*3 + ky)*3 + kx]);
  }
  const int m = i - 129024;
  if (m >= 0 && m < 18432) {
    const int e = m & 7, lane = (m >> 3) & 63;
    const int rest = m >> 9;           // ks*12+nt
    const int nt = rest % 12, ks = rest / 12;
    const int oc = nt*16 + (lane & 15);
    const int c  = ks*32 + (lane >> 4)*8 + e;
    w1p[m] = __float2bfloat16(w1w[oc*96 + c]);
  }
}

// ---------------- Kernel 1: windowed MHA, 2 windows/block, wave-per-(window,head) ----------------
// 512 thr = 8 waves; wave W = (w2,h). All global accesses are full 64B lines.
// LDS 129,924B -> 1 block/CU.
__global__ __launch_bounds__(512, 1) void attn_kernel(
    const float* __restrict__ x,
    const float* __restrict__ norm_w,
    const __hip_bfloat16* __restrict__ qkvp,
    const float* __restrict__ qkv_b,
    const __hip_bfloat16* __restrict__ projp,
    const float* __restrict__ proj_b,
    const float* __restrict__ bias_table,
    float* __restrict__ out)
{
  extern __shared__ char smem[];
  ushort* xn   = (ushort*)smem;              // [128][104] bf16 xn; later o; later outT[96][132]
  float*  btab = (float*)(smem + 129024);    // [225]

  const int wp = blockIdx.x;                 // window pair
  const int b   = wp >> 9;
  const int wy  = (wp >> 4) & 31;
  const int wxp = wp & 15;
  const int t  = threadIdx.x;
  const int y0 = wy*8, x0 = wxp*16;
  const int l  = t & 63;
  const int W  = __builtin_amdgcn_readfirstlane(t >> 6);
  const int w2 = W >> 2, h = W & 3;
  const int lr = l & 15, g = l >> 4;

  char* rbase = smem + 26624 + W*12800;      // per-(w2,h) region
  ushort* Qs = (ushort*)rbase;               // [64][32]
  ushort* Ks = (ushort*)(rbase + 4096);      // [64][32]
  ushort* Vt = (ushort*)(rbase + 8192);      // [32 d][72 tok] stride 144B
  ushort* Ps = Qs;                           // [64 rows][128B] swizzled, overlays Q+K

  for (int i = t; i < 225; i += 512) btab[i] = bias_table[i];

  // ---- P1: load window pair -> xn bf16 raw; full 64B lines ----
  for (int e = t; e < 3072; e += 512) {
    const int c = e >> 5, q5 = e & 31;
    const int ty = q5 >> 2, tq = q5 & 3;
    const float4 v = *(const float4*)(x + (size_t)(b*CC+c)*65536 + (size_t)(y0+ty)*256 + x0 + tq*4);
    const int row = (tq >> 1)*64 + ty*8 + (tq & 1)*4;
    xn[(row+0)*104+c] = f2bf(v.x); xn[(row+1)*104+c] = f2bf(v.y);
    xn[(row+2)*104+c] = f2bf(v.z); xn[(row+3)*104+c] = f2bf(v.w);
  }
  __syncthreads();

  // ---- P1.5: RMSNorm in place (sumsq from bf16; 4 lanes/row) ----
  {
    const int n = t >> 2, c0 = (t & 3) * 24;
    short8 raw[3];
    #pragma unroll
    for (int k2 = 0; k2 < 3; k2++) raw[k2] = *(const short8*)(xn + n*104 + c0 + k2*8);
    float xv[24]; float ss = 0.f;
    #pragma unroll
    for (int k2 = 0; k2 < 3; k2++)
      #pragma unroll
      for (int q = 0; q < 8; q++) { const float u = bf2f((ushort)raw[k2][q]); xv[k2*8+q] = u; ss += u*u; }
    ss += __shfl_xor(ss, 1);
    ss += __shfl_xor(ss, 2);
    const float s = rsqrtf(ss * (1.f/96.f) + 1e-6f);
    #pragma unroll
    for (int k2 = 0; k2 < 3; k2++) {
      short8 pk;
      #pragma unroll
      for (int q = 0; q < 8; q++) pk[q] = (short)f2bf(xv[k2*8+q] * s * norm_w[c0 + k2*8 + q]);
      *(short8*)(xn + n*104 + c0 + k2*8) = pk;
    }
  }
  __syncthreads();

  // ---- P2: QKV GEMM for (window w2, head h): M=64, N=96, K=96 ----
  f32x4 acc[4][6];
  #pragma unroll
  for (int mt = 0; mt < 4; mt++)
    #pragma unroll
    for (int nt = 0; nt < 6; nt++) acc[mt][nt] = (f32x4)0.f;

  #pragma unroll
  for (int ks = 0; ks < 3; ks++) {
    short8 afr[4];
    #pragma unroll
    for (int mt = 0; mt < 4; mt++)
      afr[mt] = *(const short8*)((const char*)xn + (w2*64 + lr + mt*16)*208 + g*16 + ks*64);
    #pragma unroll
    for (int nt = 0; nt < 6; nt++) {
      const short8 bfr = *(const short8*)(qkvp + ((h*3+ks)*6+nt)*512 + l*8);
      #pragma unroll
      for (int mt = 0; mt < 4; mt++)
        acc[mt][nt] = __builtin_amdgcn_mfma_f32_16x16x32_bf16(afr[mt], bfr, acc[mt][nt], 0, 0, 0);
    }
  }
  __syncthreads();   // all xn reads done (xn region becomes o later)

  // ---- write Q,K (u16) and Vt (short4v transposed); region-private ----
  #pragma unroll
  for (int nt = 0; nt < 4; nt++) {
    const int sec  = nt >> 1;
    const int dcol = lr + (nt & 1)*16;
    ushort* dst = sec ? Ks : Qs;
    const float bias = (dcol < 24) ? qkv_b[sec*96 + h*24 + dcol] : 0.f;
    #pragma unroll
    for (int mt = 0; mt < 4; mt++)
      #pragma unroll
      for (int r = 0; r < 4; r++) {
        const int row = g*4 + r + mt*16;
        const float val = (dcol < 24) ? (acc[mt][nt][r] + bias) : 0.f;
        dst[row*32 + dcol] = f2bf(val);
      }
  }
  #pragma unroll
  for (int nt = 4; nt < 6; nt++) {
    const int vd = lr + (nt-4)*16;
    const float bias = (vd < 24) ? qkv_b[192 + h*24 + vd] : 0.f;
    #pragma unroll
    for (int mt = 0; mt < 4; mt++) {
      short4v pk;
      #pragma unroll
      for (int r = 0; r < 4; r++) {
        const float val = (vd < 24) ? (acc[mt][nt][r] + bias) : 0.f;
        pk[r] = (short)f2bf(val);
      }
      *(short4v*)((char*)Vt + vd*144 + (g*4 + mt*16)*2) = pk;
    }
  }

  // ---- P3: scores = mfma(Q, K); same-wave region, no barrier ----
  f32x4 sacc[4][4];
  {
    short8 qf[4], kf[4];
    #pragma unroll
    for (int mt = 0; mt < 4; mt++) qf[mt] = *(const short8*)((char*)Qs + (lr+mt*16)*64 + g*16);
    #pragma unroll
    for (int nt = 0; nt < 4; nt++) kf[nt] = *(const short8*)((char*)Ks + (lr+nt*16)*64 + g*16);
    #pragma unroll
    for (int mt = 0; mt < 4; mt++)
      #pragma unroll
      for (int nt = 0; nt < 4; nt++)
        sacc[mt][nt] = __builtin_amdgcn_mfma_f32_16x16x32_bf16(qf[mt], kf[nt], (f32x4)0.f, 0, 0, 0);
  }

  // ---- softmax (+scale+bias), write P swizzled bf16 ----
  {
    const float SCALE = 0.20412414523193154f;
    int bk[4];
    #pragma unroll
    for (int nt = 0; nt < 4; nt++) {
      const int k = lr + nt*16;
      bk[nt] = 112 - ((k >> 3)*15 + (k & 7));
    }
    #pragma unroll
    for (int mt = 0; mt < 4; mt++)
      #pragma unroll
      for (int r = 0; r < 4; r++) {
        const int q  = g*4 + r + mt*16;
        const int aq = (q >> 3)*15 + (q & 7);
        float v[4];
        #pragma unroll
        for (int nt = 0; nt < 4; nt++) v[nt] = sacc[mt][nt][r]*SCALE + btab[aq + bk[nt]];
        float mx = fmaxf(fmaxf(v[0], v[1]), fmaxf(v[2], v[3]));
        mx = fmaxf(mx, __shfl_xor(mx, 1));
        mx = fmaxf(mx, __shfl_xor(mx, 2));
        mx = fmaxf(mx, __shfl_xor(mx, 4));
        mx = fmaxf(mx, __shfl_xor(mx, 8));
        float e[4], s = 0.f;
        #pragma unroll
        for (int nt = 0; nt < 4; nt++) { e[nt] = __expf(v[nt]-mx); s += e[nt]; }
        s += __shfl_xor(s, 1); s += __shfl_xor(s, 2);
        s += __shfl_xor(s, 4); s += __shfl_xor(s, 8);
        const float rinv = 1.0f / s;
        const int sw = (q & 7) << 4;
        #pragma unroll
        for (int nt = 0; nt < 4; nt++) {
          const int kk = (lr + nt*16)*2;
          *(ushort*)((char*)Ps + q*128 + (kk ^ sw)) = f2bf(e[nt]*rinv);
        }
      }
  }

  // ---- P4: o = mfma(P, Vt), write into xn (rows w2*64+, cols h*24+) ----
  {
    f32x4 oacc[4][2];
    #pragma unroll
    for (int mt = 0; mt < 4; mt++) { oacc[mt][0] = (f32x4)0.f; oacc[mt][1] = (f32x4)0.f; }
    #pragma unroll
    for (int ks = 0; ks < 2; ks++) {
      short8 pf[4], vf[2];
      #pragma unroll
      for (int mt = 0; mt < 4; mt++) {
        const int row = lr + mt*16;
        pf[mt] = *(const short8*)((char*)Ps + row*128 + ((g*16 + ks*64) ^ ((row & 7) << 4)));
      }
      #pragma unroll
      for (int nt = 0; nt < 2; nt++)
        vf[nt] = *(const short8*)((char*)Vt + (lr+nt*16)*144 + g*16 + ks*64);
      #pragma unroll
      for (int mt = 0; mt < 4; mt++)
        #pragma unroll
        for (int nt = 0; nt < 2; nt++)
          oacc[mt][nt] = __builtin_amdgcn_mfma_f32_16x16x32_bf16(pf[mt], vf[nt], oacc[mt][nt], 0, 0, 0);
    }
    ushort* oM = xn;
    #pragma unroll
    for (int nt = 0; nt < 2; nt++) {
      const int d0 = lr + nt*16;
      if (d0 < 24) {
        #pragma unroll
        for (int mt = 0; mt < 4; mt++)
          #pragma unroll
          for (int r = 0; r < 4; r++) {
            const int row = w2*64 + g*4 + r + mt*16;
            oM[row*104 + h*24 + d0] = f2bf(oacc[mt][nt][r]);
          }
      }
    }
  }
  __syncthreads();   // o complete (all waves)

  // ---- P5: proj: wave W owns mtile W (rows W*16..W*16+15 of 128), K=96 ----
  {
    f32x4 pacc[6];
    #pragma unroll
    for (int nt = 0; nt < 6; nt++) pacc[nt] = (f32x4)0.f;
    #pragma unroll
    for (int ks = 0; ks < 3; ks++) {
      const short8 af = *(const short8*)((const char*)xn + (lr + W*16)*208 + g*16 + ks*64);
      #pragma unroll
      for (int nt = 0; nt < 6; nt++) {
        const short8 bf = *(const short8*)(projp + (ks*6+nt)*512 + l*8);
        pacc[nt] = __builtin_amdgcn_mfma_f32_16x16x32_bf16(af, bf, pacc[nt], 0, 0, 0);
      }
    }
    __syncthreads();   // all o reads done; xn becomes outT[96][132]
    ushort* oT = xn;
    #pragma unroll
    for (int nt = 0; nt < 6; nt++) {
      const int oc = lr + nt*16;
      const float bias = proj_b[oc];
      short4v pk;
      #pragma unroll
      for (int r = 0; r < 4; r++) pk[r] = (short)f2bf(pacc[nt][r] + bias);
      *(short4v*)((char*)oT + oc*264 + (g*4 + W*16)*2) = pk;
    }
  }
  __syncthreads();

  // ---- epilogue: out = x + attn; full 64B lines ----
  {
    const ushort* oT = xn;
    #pragma unroll
    for (int k2 = 0; k2 < 6; k2++) {
      const int e = t + k2*512;
      const int oc = e >> 5, q5 = e & 31;
      const int ty = q5 >> 2, tq = q5 & 3;
      const int m = (tq >> 1)*64 + ty*8 + (tq & 1)*4;
      const short4v ov = *(const short4v*)((const char*)oT + oc*264 + m*2);
      const size_t gidx = (size_t)(b*CC+oc)*65536 + (size_t)(y0+ty)*256 + x0 + tq*4;
      float4 xv = *(const float4*)(x + gidx);
      float4 res;
      res.x = xv.x + bf2f((ushort)ov[0]);
      res.y = xv.y + bf2f((ushort)ov[1]);
      res.z = xv.z + bf2f((ushort)ov[2]);
      res.w = xv.w + bf2f((ushort)ov[3]);
      *(float4*)(out + gidx) = res;
    }
  }
}

// ---------------- Kernel 2: RMSNorm + conv1x1 + GLU via MFMA -> y bf16 [b][hw][96] ----------------
__global__ __launch_bounds__(256, 2) void mlp1_kernel(
    const float* __restrict__ x1,
    const float* __restrict__ mlp_norm_w,
    const __hip_bfloat16* __restrict__ w1p,   // [ks][12][64][8]
    const float* __restrict__ w1_b,
    __hip_bfloat16* __restrict__ y)           // [b][hw][96]
{
  __shared__ ushort xn[128*104];
  const int blk = blockIdx.x;
  const int b   = blk >> 9;
  const int p0  = (blk & 511) << 7;
  const int t   = threadIdx.x;
  const int l   = t & 63;
  const int w   = __builtin_amdgcn_readfirstlane(t >> 6);
  const int lr  = l & 15, g = l >> 4;

  {
    const int p = t >> 1, half = t & 1;
    const float* xp = x1 + (size_t)(b*CC + half*48)*65536 + p0 + p;
    float xv[48];
    float ss = 0.f;
    #pragma unroll
    for (int i = 0; i < 48; i++) { xv[i] = xp[(size_t)i*65536]; ss += xv[i]*xv[i]; }
    ss += __shfl_xor(ss, 1);
    const float s = rsqrtf(ss*(1.f/96.f) + 1e-6f);
    #pragma unroll
    for (int i = 0; i < 48; i += 2) {
      const int c = half*48 + i;
      union { ushort u[2]; uint v; } pk;
      pk.u[0] = f2bf(xv[i]   * s * mlp_norm_w[c]);
      pk.u[1] = f2bf(xv[i+1] * s * mlp_norm_w[c+1]);
      *(uint*)(&xn[p*104 + c]) = pk.v;
    }
  }
  // wave-private rows -> no barrier needed before GEMM

  f32x4 acc[2][12];
  #pragma unroll
  for (int m2 = 0; m2 < 2; m2++)
    #pragma unroll
    for (int nt = 0; nt < 12; nt++) acc[m2][nt] = (f32x4)0.f;

  #pragma unroll
  for (int ks = 0; ks < 3; ks++) {
    short8 afr[2];
    #pragma unroll
    for (int m2 = 0; m2 < 2; m2++)
      afr[m2] = *(const short8*)((const char*)xn + (lr + (w*2+m2)*16)*208 + g*16 + ks*64);
    #pragma unroll
    for (int nt = 0; nt < 12; nt++) {
      const short8 bfr = *(const short8*)(w1p + ((ks*12+nt)*64 + l)*8);
      #pragma unroll
      for (int m2 = 0; m2 < 2; m2++)
        acc[m2][nt] = __builtin_amdgcn_mfma_f32_16x16x32_bf16(afr[m2], bfr, acc[m2][nt], 0, 0, 0);
    }
  }

  #pragma unroll
  for (int m2 = 0; m2 < 2; m2++)
    #pragma unroll
    for (int nt = 0; nt < 6; nt++) {
      const int oc = nt*16 + lr;
      const float ab = w1_b[oc], gb = w1_b[96+oc];
      #pragma unroll
      for (int r = 0; r < 4; r++) {
        const int row = (w*2+m2)*16 + g*4 + r;
        const float a  = acc[m2][nt][r]   + ab;
        const float gg = acc[m2][nt+6][r] + gb;
        xn[row*104 + oc] = f2bf(a / (1.f + __expf(-gg)));
      }
    }
  __syncthreads();

  __hip_bfloat16* yp = y + ((size_t)(b*65536 + p0))*96;
  #pragma unroll
  for (int k2 = 0; k2 < 6; k2++) {
    const int e = t + k2*256;
    const int p = e / 12, ch = e - p*12;
    const short8 v = *(const short8*)(&xn[p*104 + ch*8]);
    *(short8*)((ushort*)yp + p*96 + ch*8) = v;
  }
}

// ---------------- Kernel 3: conv3x3 via MFMA implicit GEMM + leaky + residual ----------------
__global__ __launch_bounds__(256) void conv3_kernel(
    const __hip_bfloat16* __restrict__ y,    // [b][hw][96]
    const __hip_bfloat16* __restrict__ w2p,
    const float* __restrict__ w2_b,
    float* __restrict__ xout)
{
  extern __shared__ char smem[];
  ushort* A = (ushort*)smem;
  float*  O = (float*)smem;

  const int bid = blockIdx.x;
  const int b   = bid >> 9;
  const int rp  = (bid >> 2) & 127;
  const int ch  = bid & 3;
  const int px0 = ch << 6;
  const int t   = threadIdx.x;
  const int w   = __builtin_amdgcn_readfirstlane(t >> 6);
  const int l   = t & 63;
  const int m15 = l & 15, lh = l >> 4;

  for (int e = t; e < 3168; e += 256) {
    const int seg  = e / 12;
    const int part = e - seg*12;
    const int ky = seg / 66;
    const int px = seg - ky*66;
    const int gy = min(255, max(0, 2*rp + ky - 1));
    const int gx = min(255, max(0, px0 + px - 1));
    const short8 v = *(const short8*)(y + ((size_t)(b*65536 + gy*256 + gx))*96 + part*8);
    *(short8*)(A + seg*104 + part*8) = v;
  }
  __syncthreads();

  f32x4 acc0[6], acc1[6];
  #pragma unroll
  for (int nf = 0; nf < 6; ++nf) { acc0[nf] = (f32x4)0.f; acc1[nf] = (f32x4)0.f; }

  for (int tap = 0; tap < 9; ++tap) {
    const int ky = tap / 3, kx = tap - ky*3;
    for (int kc = 0; kc < 3; ++kc) {
      const int cb = kc*32 + lh*8;
      const short8 a0 = *(const short8*)(A + ((ky  )*66 + 16*w + m15 + kx)*104 + cb);
      const short8 a1 = *(const short8*)(A + ((ky+1)*66 + 16*w + m15 + kx)*104 + cb);
      const short8* bp = (const short8*)w2p + ((size_t)(tap*3 + kc)*6)*64 + l;
      #pragma unroll
      for (int nf = 0; nf < 6; ++nf) {
        const short8 bf = bp[nf*64];
        acc0[nf] = __builtin_amdgcn_mfma_f32_16x16x32_bf16(a0, bf, acc0[nf], 0, 0, 0);
        acc1[nf] = __builtin_amdgcn_mfma_f32_16x16x32_bf16(a1, bf, acc1[nf], 0, 0, 0);
      }
    }
  }
  __syncthreads();

  {
    const int jb = 16*w + lh*4;
    #pragma unroll
    for (int nf = 0; nf < 6; ++nf) {
      const int oc = nf*16 + m15;
      *(f32x4*)(O + oc*132 + jb)      = acc0[nf];
      *(f32x4*)(O + oc*132 + 64 + jb) = acc1[nf];
    }
  }
  __syncthreads();

  for (int e = t; e < 3072; e += 256) {
    const int oc = e >> 5;
    const int j  = (e & 31) * 4;
    f32x4 v = *(const f32x4*)(O + oc*132 + j);
    const float bb = w2_b[oc];
    const int gy = 2*rp + (j >> 6);
    const int px = px0 + (j & 63);
    float* op = xout + ((size_t)(b*CC + oc))*65536 + (size_t)gy*256 + px;
    f32x4 r = *(const f32x4*)op;
    #pragma unroll
    for (int q = 0; q < 4; ++q) {
      float u = v[q] + bb;
      u = (u >= 0.f) ? u : 0.1f*u;
      r[q] += u;
    }
    *(f32x4*)op = r;
  }
}

extern "C" void kernel_launch(void* const* d_in, const int* in_sizes, int n_in,
                              void* d_out, int out_size, void* d_ws, size_t ws_size,
                              hipStream_t stream)
{
  (void)in_sizes; (void)n_in; (void)out_size; (void)ws_size;
  const float* x      = (const float*)d_in[0];
  const float* norm_w = (const float*)d_in[1];
  const float* qkv_w  = (const float*)d_in[2];
  const float* qkv_b  = (const float*)d_in[3];
  const float* proj_w = (const float*)d_in[4];
  const float* proj_b = (const float*)d_in[5];
  const float* btab   = (const float*)d_in[6];
  const float* mlpnw  = (const float*)d_in[7];
  const float* w1w    = (const float*)d_in[8];
  const float* w1b    = (const float*)d_in[9];
  const float* w2w    = (const float*)d_in[10];
  const float* w2b    = (const float*)d_in[11];
  float* out = (float*)d_out;

  char* ws = (char*)d_ws;
  __hip_bfloat16* y     = (__hip_bfloat16*)ws;                    // 50,331,648 B
  __hip_bfloat16* w2p   = (__hip_bfloat16*)(ws + 50331648);       // 165,888 B
  __hip_bfloat16* qkvp  = (__hip_bfloat16*)(ws + 50497536);       // 73,728 B
  __hip_bfloat16* projp = (__hip_bfloat16*)(ws + 50571264);       // 18,432 B
  __hip_bfloat16* w1p   = (__hip_bfloat16*)(ws + 50589696);       // 36,864 B

  // opt-in for >64KB dynamic LDS (129,924B < 160KiB CU capacity)
  (void)hipFuncSetAttribute(reinterpret_cast<const void*>(attn_kernel),
                            hipFuncAttributeMaxDynamicSharedMemorySize, 129924);

  prep_kernel<<<576, 256, 0, stream>>>(qkv_w, proj_w, w2w, w1w, qkvp, projp, w2p, w1p);

  attn_kernel<<<2048, 512, 129924, stream>>>(x, norm_w, qkvp, qkv_b, projp, proj_b, btab, out);
  mlp1_kernel<<<2048, 256, 0, stream>>>(out, mlpnw, w1p, w1b, y);
  conv3_kernel<<<2048, 256, 54912, stream>>>(y, w2p, w2b, out);
}